// Round 9
// baseline (144.976 us; speedup 1.0000x reference)
//
#include <hip/hip_runtime.h>

#define NB 8192
#define NT 64
#define FCAP 5.0f

typedef unsigned int u32;
typedef float f32x4 __attribute__((ext_vector_type(4)));
typedef __bf16 bf16x8 __attribute__((ext_vector_type(8)));
typedef u32 u32x4 __attribute__((ext_vector_type(4)));
typedef u32 u32x2 __attribute__((ext_vector_type(2)));

static __device__ __forceinline__ u32 pk2(float lo, float hi) {
  u32 r;
  asm("v_cvt_pk_bf16_f32 %0, %1, %2" : "=v"(r) : "v"(lo), "v"(hi));
  return r;
}
static __device__ __forceinline__ float clipc(float a) { return fminf(fmaxf(a, -FCAP), FCAP); }

static __device__ __forceinline__ bf16x8 mkfrag(const float* __restrict__ p) {
  f32x4 a = *(const f32x4*)p, b = *(const f32x4*)(p + 4);
  u32x4 wv = {pk2(a[0], a[1]), pk2(a[2], a[3]), pk2(b[0], b[1]), pk2(b[2], b[3])};
  return __builtin_bit_cast(bf16x8, wv);
}

#define MFMA16(A, B, C) __builtin_amdgcn_mfma_f32_16x16x32_bf16(A, B, C, 0, 0, 0)

static __device__ __forceinline__ f32x4 lrelu4(f32x4 v) {
  return __builtin_elementwise_max(v, v * 0.01f);
}

// 16x16x32 bf16 layouts (HW-verified rounds 3/5):
//   A: row = lane&15, k = 32*kt + 8*(lane>>4) + e
//   B: col = lane&15, k = 32*kt + 8*(lane>>4) + e
//   C: col = lane&15, row = 4*(lane>>4) + reg
// h-buffer: buf[c][kpair] @ stride 68 words (kpair = row/2, u32 = bf16x2).
//   write: C[mt] rows 16mt+4g+r -> kpairs 8mt+2g+{0,1}: ds_write_b64 at
//          68c + 8mt + 2g
//   read:  B-frag ktile kt = words 68c + 16kt + 4g .. +3: ds_read_b128
// Both 2-way bank aliases per 16-lane quarter (c, c+8) = free (m136).
//
// SINGLE-WAVE workgroups: 512 WGs x 64 threads, 16 particles each. The FULL
// network lives in this wave's registers (aW1/aW2/aW3/aW4 ~304 VGPRs); the
// inter-layer C->B relayout goes through LDS *intra-wave* -- program-order
// lgkmcnt only, ZERO barriers, zero cross-wave handoffs. b2/b3 are broadcast-
// read from LDS as C-inits (saves 64 VGPRs). Latency-chain bound by design;
// occupancy counters will read ~3-6% -- expected, idle SIMDs cost nothing.
__global__ __launch_bounds__(64, 1) void ode_kernel(
    const float* __restrict__ ts, const float* __restrict__ y0,
    const float* __restrict__ W1, const float* __restrict__ b1,
    const float* __restrict__ W2, const float* __restrict__ b2,
    const float* __restrict__ W3, const float* __restrict__ b3,
    const float* __restrict__ W4, const float* __restrict__ b4,
    float* __restrict__ out) {
  const int l = threadIdx.x;  // 0..63
  const int g = l >> 4;       // lane group 0..3
  const int c = l & 15;       // particle col / A-row-local
  const int gp0 = blockIdx.x * 16;

  __shared__ alignas(16) u32 buf[16 * 68];   // h relayout buffer
  __shared__ alignas(16) float bls[256];     // b2 @0, b3 @128

  // ---- bias LDS (broadcast C-inits; single wave -> no barrier needed) ----
  bls[l] = b2[l];
  bls[64 + l] = b2[64 + l];
  bls[128 + l] = b3[l];
  bls[192 + l] = b3[64 + l];

  // ---- full weight set in registers ----
  bf16x8 aW2[8][4], aW3[8][4];
#pragma unroll
  for (int mt = 0; mt < 8; ++mt) {
    const int R = 16 * mt + c;
#pragma unroll
    for (int kt = 0; kt < 4; ++kt) {
      aW2[mt][kt] = mkfrag(W2 + R * 128 + 32 * kt + 8 * g);
      aW3[mt][kt] = mkfrag(W3 + R * 128 + 32 * kt + 8 * g);
    }
  }
  bf16x8 aW1[8];
#pragma unroll
  for (int mt = 0; mt < 8; ++mt) {
    const int R = 16 * mt + c;
    u32x4 f = {0, 0, 0, 0};
    if (g == 0) {
      f[0] = pk2(W1[2 * R], W1[2 * R + 1]);  // k0,k1 = W1 row
      f[1] = pk2(b1[R], 0.f);                // k2 = b1 (B carries 1.0)
    }
    aW1[mt] = __builtin_bit_cast(bf16x8, f);
  }
  bf16x8 aW4[4];
#pragma unroll
  for (int kt = 0; kt < 4; ++kt) {
    u32x4 f = {0, 0, 0, 0};
    if (c < 2) {
      const float* p = W4 + c * 128 + 32 * kt + 8 * g;
      f32x4 a = *(const f32x4*)p, b = *(const f32x4*)(p + 4);
      f = (u32x4){pk2(a[0], a[1]), pk2(a[2], a[3]), pk2(b[0], b[1]), pk2(b[2], b[3])};
    }
    aW4[kt] = __builtin_bit_cast(bf16x8, f);
  }
  const float b40 = b4[0], b41 = b4[1];

  // ---- state: only g==0 lanes track y (only they build By / store) ----
  float y1 = 0.f, y2 = 0.f;
  if (g == 0) {
    const float2 yv = *(const float2*)(y0 + (gp0 + c) * 2);
    y1 = yv.x;
    y2 = yv.y;
    float2 st = {clipc(y1), clipc(y2)};
    *(float2*)(out + (gp0 + c) * 2) = st;
  }

  const f32x4 zero4 = {0.f, 0.f, 0.f, 0.f};
  const int wbase = 68 * c + 2 * g;  // + 8*mt for writes
  const int rbase = 68 * c + 4 * g;  // + 16*kt for reads

#pragma unroll 1
  for (int t = 0; t < NT - 1; ++t) {
    const float dt = ts[t + 1] - ts[t];

    // ---- layer 1: 8 independent MFMA (W1,b1 fused in one k-tile) ----
    u32x4 byw = {0, 0, 0, 0};
    if (g == 0) {
      byw[0] = pk2(y1, y2);
      byw[1] = 0x3f80u;  // bf16(1.0)
    }
    const bf16x8 By = __builtin_bit_cast(bf16x8, byw);
    f32x4 C[8];
#pragma unroll
    for (int mt = 0; mt < 8; ++mt) C[mt] = MFMA16(aW1[mt], By, zero4);
#pragma unroll
    for (int mt = 0; mt < 8; ++mt) {
      C[mt] = lrelu4(C[mt]);
      *(__shared__ u32x2*)&buf[wbase + 8 * mt] =
          (u32x2){pk2(C[mt][0], C[mt][1]), pk2(C[mt][2], C[mt][3])};
    }
    {
      const bf16x8 q0 = __builtin_bit_cast(bf16x8, *(const __shared__ u32x4*)&buf[rbase]);
      const bf16x8 q1 = __builtin_bit_cast(bf16x8, *(const __shared__ u32x4*)&buf[rbase + 16]);
      const bf16x8 q2 = __builtin_bit_cast(bf16x8, *(const __shared__ u32x4*)&buf[rbase + 32]);
      const bf16x8 q3 = __builtin_bit_cast(bf16x8, *(const __shared__ u32x4*)&buf[rbase + 48]);
      // ---- layer 2: 8 parallel 4-deep chains, bias C-init from LDS ----
#pragma unroll
      for (int mt = 0; mt < 8; ++mt) {
        const f32x4 bias = *(const __shared__ f32x4*)&bls[16 * mt + 4 * g];
        f32x4 a = MFMA16(aW2[mt][0], q0, bias);
        a = MFMA16(aW2[mt][1], q1, a);
        a = MFMA16(aW2[mt][2], q2, a);
        C[mt] = MFMA16(aW2[mt][3], q3, a);
      }
    }
#pragma unroll
    for (int mt = 0; mt < 8; ++mt) {
      C[mt] = lrelu4(C[mt]);
      *(__shared__ u32x2*)&buf[wbase + 8 * mt] =
          (u32x2){pk2(C[mt][0], C[mt][1]), pk2(C[mt][2], C[mt][3])};
    }
    {
      const bf16x8 q0 = __builtin_bit_cast(bf16x8, *(const __shared__ u32x4*)&buf[rbase]);
      const bf16x8 q1 = __builtin_bit_cast(bf16x8, *(const __shared__ u32x4*)&buf[rbase + 16]);
      const bf16x8 q2 = __builtin_bit_cast(bf16x8, *(const __shared__ u32x4*)&buf[rbase + 32]);
      const bf16x8 q3 = __builtin_bit_cast(bf16x8, *(const __shared__ u32x4*)&buf[rbase + 48]);
      // ---- layer 3 ----
#pragma unroll
      for (int mt = 0; mt < 8; ++mt) {
        const f32x4 bias = *(const __shared__ f32x4*)&bls[128 + 16 * mt + 4 * g];
        f32x4 a = MFMA16(aW3[mt][0], q0, bias);
        a = MFMA16(aW3[mt][1], q1, a);
        a = MFMA16(aW3[mt][2], q2, a);
        C[mt] = MFMA16(aW3[mt][3], q3, a);
      }
    }
#pragma unroll
    for (int mt = 0; mt < 8; ++mt) {
      C[mt] = lrelu4(C[mt]);
      *(__shared__ u32x2*)&buf[wbase + 8 * mt] =
          (u32x2){pk2(C[mt][0], C[mt][1]), pk2(C[mt][2], C[mt][3])};
    }
    {
      const bf16x8 q0 = __builtin_bit_cast(bf16x8, *(const __shared__ u32x4*)&buf[rbase]);
      const bf16x8 q1 = __builtin_bit_cast(bf16x8, *(const __shared__ u32x4*)&buf[rbase + 16]);
      const bf16x8 q2 = __builtin_bit_cast(bf16x8, *(const __shared__ u32x4*)&buf[rbase + 32]);
      const bf16x8 q3 = __builtin_bit_cast(bf16x8, *(const __shared__ u32x4*)&buf[rbase + 48]);
      // ---- layer 4: rows 0,1 -> C4[0],C4[1] at g==0 ----
      f32x4 D = MFMA16(aW4[0], q0, zero4);
      f32x4 E = MFMA16(aW4[1], q1, zero4);
      D = MFMA16(aW4[2], q2, D);
      E = MFMA16(aW4[3], q3, E);
      const f32x4 C4 = D + E;

      if (g == 0) {
        const float f0 = C4[0] + b40;
        const float f1v = C4[1] + b41;
        y1 += dt * (f0 - y1);
        y2 += dt * (f1v - y2);
        float2 st = {clipc(y1), clipc(y2)};
        *(float2*)(out + (t + 1) * (NB * 2) + (gp0 + c) * 2) = st;
      }
    }
  }
}

extern "C" void kernel_launch(void* const* d_in, const int* in_sizes, int n_in,
                              void* d_out, int out_size, void* d_ws, size_t ws_size,
                              hipStream_t stream) {
  const float* ts = (const float*)d_in[0];
  const float* y0 = (const float*)d_in[1];
  const float* W1 = (const float*)d_in[2];
  const float* b1 = (const float*)d_in[3];
  const float* W2 = (const float*)d_in[4];
  const float* b2 = (const float*)d_in[5];
  const float* W3 = (const float*)d_in[6];
  const float* b3 = (const float*)d_in[7];
  const float* W4 = (const float*)d_in[8];
  const float* b4 = (const float*)d_in[9];

  ode_kernel<<<NB / 16, 64, 0, stream>>>(ts, y0, W1, b1, W2, b2, W3, b3, W4, b4,
                                         (float*)d_out);
}

// Round 10
// 108.238 us; speedup vs baseline: 1.3394x; 1.3394x over previous
//
#include <hip/hip_runtime.h>

#define NB 8192
#define NT 64
#define FCAP 5.0f

typedef unsigned int u32;
typedef float f32x4 __attribute__((ext_vector_type(4)));
typedef __bf16 bf16x8 __attribute__((ext_vector_type(8)));
typedef u32 u32x4 __attribute__((ext_vector_type(4)));
typedef u32 u32x2 __attribute__((ext_vector_type(2)));

static __device__ __forceinline__ u32 pk2(float lo, float hi) {
  u32 r;
  asm("v_cvt_pk_bf16_f32 %0, %1, %2" : "=v"(r) : "v"(lo), "v"(hi));
  return r;
}
static __device__ __forceinline__ float clipc(float a) { return fminf(fmaxf(a, -FCAP), FCAP); }

static __device__ __forceinline__ bf16x8 mkfrag(const float* __restrict__ p) {
  f32x4 a = *(const f32x4*)p, b = *(const f32x4*)(p + 4);
  u32x4 wv = {pk2(a[0], a[1]), pk2(a[2], a[3]), pk2(b[0], b[1]), pk2(b[2], b[3])};
  return __builtin_bit_cast(bf16x8, wv);
}

#define MFMA16(A, B, C) __builtin_amdgcn_mfma_f32_16x16x32_bf16(A, B, C, 0, 0, 0)

static __device__ __forceinline__ f32x4 lrelu4(f32x4 v) {
  return __builtin_elementwise_max(v, v * 0.01f);
}

// 16x16x32 bf16 layouts (HW-verified rounds 3/5):
//   A: row = lane&15, k = 32*kt + 8*(lane>>4) + e
//   B: col = lane&15, k = 32*kt + 8*(lane>>4) + e
//   C: col = lane&15, row = 4*(lane>>4) + reg
// h-buffer: buf[c][kpair] @ stride 68 words; write ds_write_b64 at
// 68c+16wv+2g (+8 for M-tile 1), read ds_read_b128 at 68c+4g (+16kt).
//
// DUAL-SET interleave: 256 WGs x 256 threads, each WG runs TWO independent
// 16-particle sets (X, Y) offset by half a step. Wave wv owns rows
// 32wv..32wv+31 for both sets (weights shared -> no VGPR growth). Each
// barrier-section pairs one X unit with an independent Y unit, so every
// post-barrier LDS-read chain has the other set's MFMA block in-stream to
// hide under (guaranteed ILP, unlike cross-WG/wave arbitration). L4 is
// computed fully per wave (4 k-tiles) with redundant Euler -> y stays in
// registers, no fbuf round-trip. 4 barriers advance BOTH sets one step.
__global__ __launch_bounds__(256, 1) void ode_kernel(
    const float* __restrict__ ts, const float* __restrict__ y0,
    const float* __restrict__ W1, const float* __restrict__ b1,
    const float* __restrict__ W2, const float* __restrict__ b2,
    const float* __restrict__ W3, const float* __restrict__ b3,
    const float* __restrict__ W4, const float* __restrict__ b4,
    float* __restrict__ out) {
  const int tid = threadIdx.x;
  const int wv = __builtin_amdgcn_readfirstlane(tid >> 6);  // wave 0..3
  const int l = tid & 63;
  const int g = l >> 4;   // lane group 0..3
  const int c = l & 15;   // particle col / A-row-local
  const int gp0 = blockIdx.x * 32;

  __shared__ alignas(16) u32 hx1[16 * 68], hx2[16 * 68], hx3[16 * 68];
  __shared__ alignas(16) u32 hy1[16 * 68], hy2[16 * 68], hy3[16 * 68];

  // ---- weights (identical to R5, shared by both sets) ----
  bf16x8 aW2[2][4], aW3[2][4];
#pragma unroll
  for (int mt = 0; mt < 2; ++mt) {
    const int R = 32 * wv + 16 * mt + c;
#pragma unroll
    for (int kt = 0; kt < 4; ++kt) {
      aW2[mt][kt] = mkfrag(W2 + R * 128 + 32 * kt + 8 * g);
      aW3[mt][kt] = mkfrag(W3 + R * 128 + 32 * kt + 8 * g);
    }
  }
  bf16x8 aW1[2];
#pragma unroll
  for (int mt = 0; mt < 2; ++mt) {
    const int R = 32 * wv + 16 * mt + c;
    u32x4 f = {0, 0, 0, 0};
    if (g == 0) {
      f[0] = pk2(W1[2 * R], W1[2 * R + 1]);  // k0,k1 = W1 row
      f[1] = pk2(b1[R], 0.f);                // k2 = b1 (B carries 1.0)
    }
    aW1[mt] = __builtin_bit_cast(bf16x8, f);
  }
  bf16x8 aW4[4];  // full K=128 (4 k-tiles), rows 0,1 = W4
#pragma unroll
  for (int kt = 0; kt < 4; ++kt) {
    u32x4 f = {0, 0, 0, 0};
    if (c < 2) {
      const float* p = W4 + c * 128 + 32 * kt + 8 * g;
      f32x4 a = *(const f32x4*)p, b = *(const f32x4*)(p + 4);
      f = (u32x4){pk2(a[0], a[1]), pk2(a[2], a[3]), pk2(b[0], b[1]), pk2(b[2], b[3])};
    }
    aW4[kt] = __builtin_bit_cast(bf16x8, f);
  }
  f32x4 cb2[2], cb3[2];
#pragma unroll
  for (int mt = 0; mt < 2; ++mt) {
#pragma unroll
    for (int r = 0; r < 4; ++r) {
      const int row = 32 * wv + 16 * mt + 4 * g + r;
      cb2[mt][r] = b2[row];
      cb3[mt][r] = b3[row];
    }
  }
  const float b40 = b4[0], b41 = b4[1];

  // ---- state: g==0 lanes of EVERY wave track y for both sets ----
  float yx1 = 0.f, yx2 = 0.f, yy1 = 0.f, yy2 = 0.f;
  if (g == 0) {
    const float2 a = *(const float2*)(y0 + (gp0 + c) * 2);
    const float2 b = *(const float2*)(y0 + (gp0 + 16 + c) * 2);
    yx1 = a.x; yx2 = a.y;
    yy1 = b.x; yy2 = b.y;
    if (wv == 0) {
      *(float2*)(out + (gp0 + c) * 2)      = (float2){clipc(yx1), clipc(yx2)};
      *(float2*)(out + (gp0 + 16 + c) * 2) = (float2){clipc(yy1), clipc(yy2)};
    }
  }

  const f32x4 zero4 = {0.f, 0.f, 0.f, 0.f};
  const int wbase = 68 * c + 16 * wv + 2 * g;
  const int rbase = 68 * c + 4 * g;

  auto L1 = [&](u32* dst, float y1, float y2) {
    u32x4 byw = {0, 0, 0, 0};
    if (g == 0) {
      byw[0] = pk2(y1, y2);
      byw[1] = 0x3f80u;  // bf16(1.0)
    }
    const bf16x8 By = __builtin_bit_cast(bf16x8, byw);
    const f32x4 C0 = lrelu4(MFMA16(aW1[0], By, zero4));
    const f32x4 C1 = lrelu4(MFMA16(aW1[1], By, zero4));
    *(__shared__ u32x2*)&dst[wbase]     = (u32x2){pk2(C0[0], C0[1]), pk2(C0[2], C0[3])};
    *(__shared__ u32x2*)&dst[wbase + 8] = (u32x2){pk2(C1[0], C1[1]), pk2(C1[2], C1[3])};
  };
  auto L23 = [&](const u32* src, u32* dst, const bf16x8 (&A)[2][4], const f32x4 (&cb)[2]) {
    const bf16x8 q0 = __builtin_bit_cast(bf16x8, *(const __shared__ u32x4*)&src[rbase]);
    const bf16x8 q1 = __builtin_bit_cast(bf16x8, *(const __shared__ u32x4*)&src[rbase + 16]);
    const bf16x8 q2 = __builtin_bit_cast(bf16x8, *(const __shared__ u32x4*)&src[rbase + 32]);
    const bf16x8 q3 = __builtin_bit_cast(bf16x8, *(const __shared__ u32x4*)&src[rbase + 48]);
    f32x4 D0 = MFMA16(A[0][0], q0, cb[0]);
    f32x4 D1 = MFMA16(A[1][0], q0, cb[1]);
    f32x4 E0 = MFMA16(A[0][1], q1, zero4);
    f32x4 E1 = MFMA16(A[1][1], q1, zero4);
    D0 = MFMA16(A[0][2], q2, D0);
    D1 = MFMA16(A[1][2], q2, D1);
    E0 = MFMA16(A[0][3], q3, E0);
    E1 = MFMA16(A[1][3], q3, E1);
    const f32x4 C0 = lrelu4(D0 + E0);
    const f32x4 C1 = lrelu4(D1 + E1);
    *(__shared__ u32x2*)&dst[wbase]     = (u32x2){pk2(C0[0], C0[1]), pk2(C0[2], C0[3])};
    *(__shared__ u32x2*)&dst[wbase + 8] = (u32x2){pk2(C1[0], C1[1]), pk2(C1[2], C1[3])};
  };
  auto L4E = [&](const u32* src, float& y1, float& y2, float dt, int t, int pofs) {
    const bf16x8 q0 = __builtin_bit_cast(bf16x8, *(const __shared__ u32x4*)&src[rbase]);
    const bf16x8 q1 = __builtin_bit_cast(bf16x8, *(const __shared__ u32x4*)&src[rbase + 16]);
    const bf16x8 q2 = __builtin_bit_cast(bf16x8, *(const __shared__ u32x4*)&src[rbase + 32]);
    const bf16x8 q3 = __builtin_bit_cast(bf16x8, *(const __shared__ u32x4*)&src[rbase + 48]);
    f32x4 D = MFMA16(aW4[0], q0, zero4);
    f32x4 E = MFMA16(aW4[1], q1, zero4);
    D = MFMA16(aW4[2], q2, D);
    E = MFMA16(aW4[3], q3, E);
    const f32x4 C4 = D + E;
    if (g == 0) {  // Euler redundant in every wave; store from wave 0 only
      const float f0 = C4[0] + b40;
      const float f1v = C4[1] + b41;
      y1 += dt * (f0 - y1);
      y2 += dt * (f1v - y2);
      if (wv == 0) {
        *(float2*)(out + (t + 1) * (NB * 2) + (gp0 + pofs + c) * 2) =
            (float2){clipc(y1), clipc(y2)};
      }
    }
  };

  // ---- prologue: X half-step ahead ----
  L1(hx1, yx1, yx2);
  __syncthreads();
  L23(hx1, hx2, aW2, cb2);
  __syncthreads();

#pragma unroll 1
  for (int t = 0; t < NT - 1; ++t) {
    const float dt = ts[t + 1] - ts[t];

    // section A: X.L3(t) || Y.L1(t)
    L23(hx2, hx3, aW3, cb3);
    L1(hy1, yy1, yy2);
    __syncthreads();

    // section B: X.L4E(t) || Y.L2(t)
    L4E(hx3, yx1, yx2, dt, t, 0);
    L23(hy1, hy2, aW2, cb2);
    __syncthreads();

    // section C: X.L1(t+1) || Y.L3(t)
    if (t < NT - 2) L1(hx1, yx1, yx2);
    L23(hy2, hy3, aW3, cb3);
    __syncthreads();

    // section D: X.L2(t+1) || Y.L4E(t)
    if (t < NT - 2) L23(hx1, hx2, aW2, cb2);
    L4E(hy3, yy1, yy2, dt, t, 16);
    __syncthreads();
  }
}

extern "C" void kernel_launch(void* const* d_in, const int* in_sizes, int n_in,
                              void* d_out, int out_size, void* d_ws, size_t ws_size,
                              hipStream_t stream) {
  const float* ts = (const float*)d_in[0];
  const float* y0 = (const float*)d_in[1];
  const float* W1 = (const float*)d_in[2];
  const float* b1 = (const float*)d_in[3];
  const float* W2 = (const float*)d_in[4];
  const float* b2 = (const float*)d_in[5];
  const float* W3 = (const float*)d_in[6];
  const float* b3 = (const float*)d_in[7];
  const float* W4 = (const float*)d_in[8];
  const float* b4 = (const float*)d_in[9];

  ode_kernel<<<NB / 32, 256, 0, stream>>>(ts, y0, W1, b1, W2, b2, W3, b3, W4, b4,
                                          (float*)d_out);
}

// Round 11
// 77.618 us; speedup vs baseline: 1.8678x; 1.3945x over previous
//
#include <hip/hip_runtime.h>

#define NB 8192
#define NT 64
#define FCAP 5.0f

typedef unsigned int u32;
typedef float f32x4 __attribute__((ext_vector_type(4)));
typedef __bf16 bf16x8 __attribute__((ext_vector_type(8)));
typedef u32 u32x4 __attribute__((ext_vector_type(4)));
typedef u32 u32x2 __attribute__((ext_vector_type(2)));

static __device__ __forceinline__ u32 pk2(float lo, float hi) {
  u32 r;
  asm("v_cvt_pk_bf16_f32 %0, %1, %2" : "=v"(r) : "v"(lo), "v"(hi));
  return r;
}
static __device__ __forceinline__ float clipc(float a) { return fminf(fmaxf(a, -FCAP), FCAP); }

static __device__ __forceinline__ bf16x8 mkfrag(const float* __restrict__ p) {
  f32x4 a = *(const f32x4*)p, b = *(const f32x4*)(p + 4);
  u32x4 wv = {pk2(a[0], a[1]), pk2(a[2], a[3]), pk2(b[0], b[1]), pk2(b[2], b[3])};
  return __builtin_bit_cast(bf16x8, wv);
}

#define MFMA16(A, B, C) __builtin_amdgcn_mfma_f32_16x16x32_bf16(A, B, C, 0, 0, 0)

static __device__ __forceinline__ f32x4 lrelu4(f32x4 v) {
  return __builtin_elementwise_max(v, v * 0.01f);
}

// lgkm-only barrier: skips __syncthreads' vmcnt(0) drain (out-stores are
// write-only, never read in-kernel -> no need to wait for HBM retirement).
// lgkmcnt(0) BEFORE s_barrier guarantees our ds_writes are visible; the
// sched_barrier(0) fence blocks compiler hoisting of post-barrier LDS reads
// (guide rule #18).
static __device__ __forceinline__ void bar_lgkm() {
  asm volatile("s_waitcnt lgkmcnt(0)" ::: "memory");
  __builtin_amdgcn_s_barrier();
  __builtin_amdgcn_sched_barrier(0);
}

// 16x16x32 bf16 layouts (HW-verified rounds 3/5):
//   A: row = lane&15, k = 32*kt + 8*(lane>>4) + e
//   B: col = lane&15, k = 32*kt + 8*(lane>>4) + e
//   C: col = lane&15, row = 4*(lane>>4) + reg
// h-buffer: buf[c][kpair] @ stride 68 words; write ds_write_b64 at
// 68c+16wv+2g (+8 for M-tile 1), read ds_read_b128 at 68c+4g (+16kt).
// fbuf stride 20 words: bank group (5c)&7 bijective in c&7 -> 2-way = free.
//
// R5 shape (512 WGs x 256 thr, 2 WG/CU, wave wv owns rows 32wv..+31,
// 16 particles/WG) with a shortened per-step critical path:
//   L1 (By local) -> w h1 -> BAR1 -> L2 (r h1, 8 MFMA) -> w h2 -> BAR2 ->
//   L3 (r h2, 8 MFMA) -> L4 IN-REGISTER (16 FMA + shfl_xor 16/32) ->
//   fbuf w -> BAR3 -> fbuf r -> Euler.
// h3 never touches LDS; all barriers are lgkm-only.
__global__ __launch_bounds__(256, 2) void ode_kernel(
    const float* __restrict__ ts, const float* __restrict__ y0,
    const float* __restrict__ W1, const float* __restrict__ b1,
    const float* __restrict__ W2, const float* __restrict__ b2,
    const float* __restrict__ W3, const float* __restrict__ b3,
    const float* __restrict__ W4, const float* __restrict__ b4,
    float* __restrict__ out) {
  const int tid = threadIdx.x;
  const int wv = __builtin_amdgcn_readfirstlane(tid >> 6);  // wave 0..3
  const int l = tid & 63;
  const int g = l >> 4;   // lane group 0..3
  const int c = l & 15;   // particle col
  const int gp0 = blockIdx.x * 16;

  __shared__ alignas(16) u32 bufA[16 * 68];    // h1
  __shared__ alignas(16) u32 bufB[16 * 68];    // h2
  __shared__ alignas(16) float fbuf[16 * 20];  // [c][wv][2] @ stride 20

  // ---- weights ----
  bf16x8 aW2[2][4], aW3[2][4];
#pragma unroll
  for (int mt = 0; mt < 2; ++mt) {
    const int R = 32 * wv + 16 * mt + c;
#pragma unroll
    for (int kt = 0; kt < 4; ++kt) {
      aW2[mt][kt] = mkfrag(W2 + R * 128 + 32 * kt + 8 * g);
      aW3[mt][kt] = mkfrag(W3 + R * 128 + 32 * kt + 8 * g);
    }
  }
  bf16x8 aW1[2];
#pragma unroll
  for (int mt = 0; mt < 2; ++mt) {
    const int R = 32 * wv + 16 * mt + c;
    u32x4 f = {0, 0, 0, 0};
    if (g == 0) {
      f[0] = pk2(W1[2 * R], W1[2 * R + 1]);  // k0,k1 = W1 row
      f[1] = pk2(b1[R], 0.f);                // k2 = b1 (B carries 1.0)
    }
    aW1[mt] = __builtin_bit_cast(bf16x8, f);
  }
  // W4 per-lane f32 for in-register L4: this lane's 8 own h3 rows
  float w40[8], w41[8];
#pragma unroll
  for (int mt = 0; mt < 2; ++mt) {
#pragma unroll
    for (int rr = 0; rr < 4; ++rr) {
      const int row = 32 * wv + 16 * mt + 4 * g + rr;
      w40[mt * 4 + rr] = W4[row];
      w41[mt * 4 + rr] = W4[128 + row];
    }
  }
  f32x4 cb2[2], cb3[2];
#pragma unroll
  for (int mt = 0; mt < 2; ++mt) {
#pragma unroll
    for (int r = 0; r < 4; ++r) {
      const int row = 32 * wv + 16 * mt + 4 * g + r;
      cb2[mt][r] = b2[row];
      cb3[mt][r] = b3[row];
    }
  }
  const float b40 = b4[0], b41 = b4[1];

  // ---- state: all lanes track y for col c ----
  float y1 = y0[(gp0 + c) * 2];
  float y2 = y0[(gp0 + c) * 2 + 1];

  if (wv == 0 && g == 0) {
    float2 st = {clipc(y1), clipc(y2)};
    *(float2*)(out + (gp0 + c) * 2) = st;
  }

  const f32x4 zero4 = {0.f, 0.f, 0.f, 0.f};
  const int wbase = 68 * c + 16 * wv + 2 * g;
  const int rbase = 68 * c + 4 * g;

#pragma unroll 1
  for (int t = 0; t < NT - 1; ++t) {
    const float dt = ts[t + 1] - ts[t];

    // ---- layer 1 (bias fused: B k0=y1,k1=y2,k2=1) ----
    u32x4 byw = {0, 0, 0, 0};
    if (g == 0) {
      byw[0] = pk2(y1, y2);
      byw[1] = 0x3f80u;  // bf16(1.0)
    }
    const bf16x8 By = __builtin_bit_cast(bf16x8, byw);
    const f32x4 C0 = lrelu4(MFMA16(aW1[0], By, zero4));
    const f32x4 C1 = lrelu4(MFMA16(aW1[1], By, zero4));
    *(__shared__ u32x2*)&bufA[wbase]     = (u32x2){pk2(C0[0], C0[1]), pk2(C0[2], C0[3])};
    *(__shared__ u32x2*)&bufA[wbase + 8] = (u32x2){pk2(C1[0], C1[1]), pk2(C1[2], C1[3])};
    bar_lgkm();  // BAR1: h1 published

    // ---- layer 2 (4-deep accumulate chains, as R5) ----
    f32x4 D0, D1;
    {
      __builtin_amdgcn_s_setprio(1);
      const bf16x8 q0 = __builtin_bit_cast(bf16x8, *(const __shared__ u32x4*)&bufA[rbase]);
      const bf16x8 q1 = __builtin_bit_cast(bf16x8, *(const __shared__ u32x4*)&bufA[rbase + 16]);
      const bf16x8 q2 = __builtin_bit_cast(bf16x8, *(const __shared__ u32x4*)&bufA[rbase + 32]);
      const bf16x8 q3 = __builtin_bit_cast(bf16x8, *(const __shared__ u32x4*)&bufA[rbase + 48]);
      D0 = MFMA16(aW2[0][0], q0, cb2[0]);
      D1 = MFMA16(aW2[1][0], q0, cb2[1]);
      D0 = MFMA16(aW2[0][1], q1, D0);
      D1 = MFMA16(aW2[1][1], q1, D1);
      D0 = MFMA16(aW2[0][2], q2, D0);
      D1 = MFMA16(aW2[1][2], q2, D1);
      D0 = MFMA16(aW2[0][3], q3, D0);
      D1 = MFMA16(aW2[1][3], q3, D1);
      __builtin_amdgcn_s_setprio(0);
      D0 = lrelu4(D0);
      D1 = lrelu4(D1);
    }
    *(__shared__ u32x2*)&bufB[wbase]     = (u32x2){pk2(D0[0], D0[1]), pk2(D0[2], D0[3])};
    *(__shared__ u32x2*)&bufB[wbase + 8] = (u32x2){pk2(D1[0], D1[1]), pk2(D1[2], D1[3])};
    bar_lgkm();  // BAR2: h2 published

    // ---- layer 3 (h3 stays in registers) ----
    f32x4 H0, H1;
    {
      __builtin_amdgcn_s_setprio(1);
      const bf16x8 q0 = __builtin_bit_cast(bf16x8, *(const __shared__ u32x4*)&bufB[rbase]);
      const bf16x8 q1 = __builtin_bit_cast(bf16x8, *(const __shared__ u32x4*)&bufB[rbase + 16]);
      const bf16x8 q2 = __builtin_bit_cast(bf16x8, *(const __shared__ u32x4*)&bufB[rbase + 32]);
      const bf16x8 q3 = __builtin_bit_cast(bf16x8, *(const __shared__ u32x4*)&bufB[rbase + 48]);
      f32x4 E0 = MFMA16(aW3[0][0], q0, cb3[0]);
      f32x4 E1 = MFMA16(aW3[1][0], q0, cb3[1]);
      E0 = MFMA16(aW3[0][1], q1, E0);
      E1 = MFMA16(aW3[1][1], q1, E1);
      E0 = MFMA16(aW3[0][2], q2, E0);
      E1 = MFMA16(aW3[1][2], q2, E1);
      E0 = MFMA16(aW3[0][3], q3, E0);
      E1 = MFMA16(aW3[1][3], q3, E1);
      __builtin_amdgcn_s_setprio(0);
      H0 = lrelu4(E0);
      H1 = lrelu4(E1);
    }

    // ---- layer 4: in-register dot (f32 h3) + cross-lane reduce ----
    float f0 = 0.f, f1 = 0.f;
#pragma unroll
    for (int rr = 0; rr < 4; ++rr) {
      f0 = fmaf(w40[rr], H0[rr], f0);
      f0 = fmaf(w40[4 + rr], H1[rr], f0);
      f1 = fmaf(w41[rr], H0[rr], f1);
      f1 = fmaf(w41[4 + rr], H1[rr], f1);
    }
    f0 += __shfl_xor(f0, 16);
    f1 += __shfl_xor(f1, 16);
    f0 += __shfl_xor(f0, 32);
    f1 += __shfl_xor(f1, 32);
    if (g == 0)
      *(__shared__ float2*)&fbuf[c * 20 + wv * 2] = (float2){f0, f1};
    bar_lgkm();  // BAR3: wave partials published

    // ---- reduce 4 wave-partials + Euler (uniform across lanes) ----
    const f32x4 pa = *(const __shared__ f32x4*)&fbuf[c * 20];
    const f32x4 pb = *(const __shared__ f32x4*)&fbuf[c * 20 + 4];
    const f32x4 s = pa + pb;
    const float ft0 = b40 + s[0] + s[2];
    const float ft1 = b41 + s[1] + s[3];
    y1 += dt * (ft0 - y1);
    y2 += dt * (ft1 - y2);

    if (wv == 0 && g == 0) {
      float2 st = {clipc(y1), clipc(y2)};
      *(float2*)(out + (t + 1) * (NB * 2) + (gp0 + c) * 2) = st;
    }
  }
}

extern "C" void kernel_launch(void* const* d_in, const int* in_sizes, int n_in,
                              void* d_out, int out_size, void* d_ws, size_t ws_size,
                              hipStream_t stream) {
  const float* ts = (const float*)d_in[0];
  const float* y0 = (const float*)d_in[1];
  const float* W1 = (const float*)d_in[2];
  const float* b1 = (const float*)d_in[3];
  const float* W2 = (const float*)d_in[4];
  const float* b2 = (const float*)d_in[5];
  const float* W3 = (const float*)d_in[6];
  const float* b3 = (const float*)d_in[7];
  const float* W4 = (const float*)d_in[8];
  const float* b4 = (const float*)d_in[9];

  ode_kernel<<<NB / 16, 256, 0, stream>>>(ts, y0, W1, b1, W2, b2, W3, b3, W4, b4,
                                          (float*)d_out);
}

// Round 12
// 67.689 us; speedup vs baseline: 2.1418x; 1.1467x over previous
//
#include <hip/hip_runtime.h>

#define NB 8192
#define NT 64
#define FCAP 5.0f

typedef unsigned int u32;
typedef float f32x4 __attribute__((ext_vector_type(4)));
typedef __bf16 bf16x8 __attribute__((ext_vector_type(8)));
typedef u32 u32x4 __attribute__((ext_vector_type(4)));
typedef u32 u32x2 __attribute__((ext_vector_type(2)));

static __device__ __forceinline__ u32 pk2(float lo, float hi) {
  u32 r;
  asm("v_cvt_pk_bf16_f32 %0, %1, %2" : "=v"(r) : "v"(lo), "v"(hi));
  return r;
}
static __device__ __forceinline__ float clipc(float a) { return fminf(fmaxf(a, -FCAP), FCAP); }

// pack 8 consecutive f32 into one bf16x8 fragment (RNE)
static __device__ __forceinline__ bf16x8 mkfrag(const float* __restrict__ p) {
  f32x4 a = *(const f32x4*)p, b = *(const f32x4*)(p + 4);
  u32x4 wv = {pk2(a[0], a[1]), pk2(a[2], a[3]), pk2(b[0], b[1]), pk2(b[2], b[3])};
  return __builtin_bit_cast(bf16x8, wv);
}

#define MFMA16(A, B, C) __builtin_amdgcn_mfma_f32_16x16x32_bf16(A, B, C, 0, 0, 0)

// leaky_relu on 4 packed f32
static __device__ __forceinline__ f32x4 lrelu4(f32x4 v) {
  return __builtin_elementwise_max(v, v * 0.01f);
}

// 16x16x32 bf16 layouts (HW-verified rounds 3/5):
//   A: row = lane&15, k = 32*kt + 8*(lane>>4) + e
//   B: col = lane&15, k = 32*kt + 8*(lane>>4) + e
//   C: col = lane&15, row = 4*(lane>>4) + reg
// h-buffer: buf[c][kpair] @ stride 68 words; write ds_write_b64 at
// 68c+16wv+2g (+8 for M-tile 1), read ds_read_b128 at 68c+4g (+16kt).
// fbuf stride 20 words: float4 read at 20c hits bank-group (5c)&7 --
// bijective in c&7 -> 2 lanes/group = free (stride 8 was 4-way, R5: 9.16M).
//
// R5 champion structure (512 WGs x 256 thr, 2 WG/CU, wave wv owns rows
// 32wv..+31, 16 particles/WG, 3 __syncthreads/step) + ANTI-PHASE STAGGER:
// co-resident WG pairs differ by 256 in blockIdx.x (XCD round-robin
// dispatch: bid and bid+256 -> same CU). The pair launches together and
// convoys (both wait at barriers simultaneously -> wall = 2x path, matching
// the measured 2460 cyc/step vs ~1200 path). A one-time ~1216-cycle sleep
// for the upper half anti-phases the pair so each WG computes while the
// other waits. Deterministic; worst case (mapping wrong) it's a no-op.
__global__ __launch_bounds__(256, 2) void ode_kernel(
    const float* __restrict__ ts, const float* __restrict__ y0,
    const float* __restrict__ W1, const float* __restrict__ b1,
    const float* __restrict__ W2, const float* __restrict__ b2,
    const float* __restrict__ W3, const float* __restrict__ b3,
    const float* __restrict__ W4, const float* __restrict__ b4,
    float* __restrict__ out) {
  const int tid = threadIdx.x;
  const int wv = __builtin_amdgcn_readfirstlane(tid >> 6);  // wave 0..3
  const int l = tid & 63;
  const int g = l >> 4;   // lane group 0..3
  const int c = l & 15;   // particle col / A-row-local
  const int gp0 = blockIdx.x * 16;

  __shared__ alignas(16) u32 bufA[16 * 68];
  __shared__ alignas(16) u32 bufB[16 * 68];
  __shared__ alignas(16) float fbuf[16 * 20];  // [c][wv][2] @ stride 20

  // ---- A-fragments (one-time, f32 -> bf16 RNE) ----
  bf16x8 aW2[2][4], aW3[2][4];
#pragma unroll
  for (int mt = 0; mt < 2; ++mt) {
    const int R = 32 * wv + 16 * mt + c;
#pragma unroll
    for (int kt = 0; kt < 4; ++kt) {
      aW2[mt][kt] = mkfrag(W2 + R * 128 + 32 * kt + 8 * g);
      aW3[mt][kt] = mkfrag(W3 + R * 128 + 32 * kt + 8 * g);
    }
  }
  // L1: k0,k1 = W1 row, k2 = b1 (B supplies y1,y2,1)
  bf16x8 aW1[2];
#pragma unroll
  for (int mt = 0; mt < 2; ++mt) {
    const int R = 32 * wv + 16 * mt + c;
    u32x4 f = {0, 0, 0, 0};
    if (g == 0) {
      f[0] = pk2(W1[2 * R], W1[2 * R + 1]);
      f[1] = pk2(b1[R], 0.f);
    }
    aW1[mt] = __builtin_bit_cast(bf16x8, f);
  }
  // L4: A rows 0,1 = W4 over this wave's k-range [32wv, 32wv+32)
  bf16x8 aW4;
  {
    u32x4 f = {0, 0, 0, 0};
    if (c < 2) {
      const float* s = W4 + c * 128 + 32 * wv + 8 * g;
      f32x4 a = *(const f32x4*)s, b = *(const f32x4*)(s + 4);
      f = (u32x4){pk2(a[0], a[1]), pk2(a[2], a[3]), pk2(b[0], b[1]), pk2(b[2], b[3])};
    }
    aW4 = __builtin_bit_cast(bf16x8, f);
  }
  // b2/b3 as C-init registers: C row = 32wv + 16mt + 4g + r
  f32x4 cb2[2], cb3[2];
#pragma unroll
  for (int mt = 0; mt < 2; ++mt) {
#pragma unroll
    for (int r = 0; r < 4; ++r) {
      const int row = 32 * wv + 16 * mt + 4 * g + r;
      cb2[mt][r] = b2[row];
      cb3[mt][r] = b3[row];
    }
  }
  const float b40 = b4[0], b41 = b4[1];

  // ---- state: all lanes track y for col c (uniform across g, wv) ----
  float y1 = y0[(gp0 + c) * 2];
  float y2 = y0[(gp0 + c) * 2 + 1];

  if (wv == 0 && g == 0) {
    float2 st = {clipc(y1), clipc(y2)};
    *(float2*)(out + (gp0 + c) * 2) = st;
  }

  // ---- anti-phase stagger: upper half of grid sleeps ~1216 cyc once ----
  if (blockIdx.x & 256) {
    __builtin_amdgcn_s_sleep(19);
  }

  const f32x4 zero4 = {0.f, 0.f, 0.f, 0.f};
  const int wbase = 68 * c + 16 * wv + 2 * g;  // write word base (M-tile 0)
  const int rbase = 68 * c + 4 * g;            // read word base (k-tile 0)

#pragma unroll 1
  for (int t = 0; t < NT - 1; ++t) {
    const float dt = ts[t + 1] - ts[t];

    // ---- layer 1 (bias fused: B k0=y1,k1=y2,k2=1) ----
    u32x4 byw = {0, 0, 0, 0};
    if (g == 0) {
      byw[0] = pk2(y1, y2);
      byw[1] = 0x3f80u;  // bf16(1.0) in lo half
    }
    const bf16x8 By = __builtin_bit_cast(bf16x8, byw);
    f32x4 C0 = MFMA16(aW1[0], By, zero4);
    f32x4 C1 = MFMA16(aW1[1], By, zero4);
    C0 = lrelu4(C0);
    C1 = lrelu4(C1);
    *(__shared__ u32x2*)&bufA[wbase]     = (u32x2){pk2(C0[0], C0[1]), pk2(C0[2], C0[3])};
    *(__shared__ u32x2*)&bufA[wbase + 8] = (u32x2){pk2(C1[0], C1[1]), pk2(C1[2], C1[3])};
    __syncthreads();

    // ---- layer 2 ----
    f32x4 D0 = cb2[0], D1 = cb2[1];
#pragma unroll
    for (int kt = 0; kt < 4; ++kt) {
      const bf16x8 q =
          __builtin_bit_cast(bf16x8, *(const __shared__ u32x4*)&bufA[rbase + 16 * kt]);
      D0 = MFMA16(aW2[0][kt], q, D0);
      D1 = MFMA16(aW2[1][kt], q, D1);
    }
    D0 = lrelu4(D0);
    D1 = lrelu4(D1);
    *(__shared__ u32x2*)&bufB[wbase]     = (u32x2){pk2(D0[0], D0[1]), pk2(D0[2], D0[3])};
    *(__shared__ u32x2*)&bufB[wbase + 8] = (u32x2){pk2(D1[0], D1[1]), pk2(D1[2], D1[3])};
    __syncthreads();

    // ---- layer 3 (h3 -> bufA; safe: all waves are past their L2 reads) ----
    f32x4 E0 = cb3[0], E1 = cb3[1];
#pragma unroll
    for (int kt = 0; kt < 4; ++kt) {
      const bf16x8 q =
          __builtin_bit_cast(bf16x8, *(const __shared__ u32x4*)&bufB[rbase + 16 * kt]);
      E0 = MFMA16(aW3[0][kt], q, E0);
      E1 = MFMA16(aW3[1][kt], q, E1);
    }
    E0 = lrelu4(E0);
    E1 = lrelu4(E1);
    *(__shared__ u32x2*)&bufA[wbase]     = (u32x2){pk2(E0[0], E0[1]), pk2(E0[2], E0[3])};
    *(__shared__ u32x2*)&bufA[wbase + 8] = (u32x2){pk2(E1[0], E1[1]), pk2(E1[2], E1[3])};

    // ---- layer 4: k-tile wv is self-owned -> no barrier, just lgkmcnt ----
    const bf16x8 q3v =
        __builtin_bit_cast(bf16x8, *(const __shared__ u32x4*)&bufA[rbase + 16 * wv]);
    f32x4 C4 = MFMA16(aW4, q3v, zero4);
    if (g == 0)
      *(__shared__ float2*)&fbuf[c * 20 + wv * 2] = (float2){C4[0], C4[1]};
    __syncthreads();

    // ---- reduce 4 wave-partials + Euler update (uniform across lanes) ----
    const f32x4 pa = *(const __shared__ f32x4*)&fbuf[c * 20];
    const f32x4 pb = *(const __shared__ f32x4*)&fbuf[c * 20 + 4];
    const f32x4 s = pa + pb;  // v_pk_add_f32
    const float f0 = b40 + s[0] + s[2];
    const float f1v = b41 + s[1] + s[3];
    y1 += dt * (f0 - y1);
    y2 += dt * (f1v - y2);

    if (wv == 0 && g == 0) {
      float2 st = {clipc(y1), clipc(y2)};
      *(float2*)(out + (t + 1) * (NB * 2) + (gp0 + c) * 2) = st;
    }
  }
}

extern "C" void kernel_launch(void* const* d_in, const int* in_sizes, int n_in,
                              void* d_out, int out_size, void* d_ws, size_t ws_size,
                              hipStream_t stream) {
  const float* ts = (const float*)d_in[0];
  const float* y0 = (const float*)d_in[1];
  const float* W1 = (const float*)d_in[2];
  const float* b1 = (const float*)d_in[3];
  const float* W2 = (const float*)d_in[4];
  const float* b2 = (const float*)d_in[5];
  const float* W3 = (const float*)d_in[6];
  const float* b3 = (const float*)d_in[7];
  const float* W4 = (const float*)d_in[8];
  const float* b4 = (const float*)d_in[9];

  ode_kernel<<<NB / 16, 256, 0, stream>>>(ts, y0, W1, b1, W2, b2, W3, b3, W4, b4,
                                          (float*)d_out);
}